// Round 2
// baseline (1116.825 us; speedup 1.0000x reference)
//
#include <hip/hip_runtime.h>

// Depthwise causal conv1d: x (4, 2048, 8192) f32, weight (2048,1,16) f32, bias (2048) f32.
// out[n,c,l] = sum_{k=0..15} x[n,c,l+k-15] * w[c,k] + bias[c]   (x index <0 -> 0)
// Memory-bound: 512 MiB traffic -> ~85us floor @ 6.3 TB/s.

#define DIMC 2048
#define LEN 8192
#define KW 16
#define CHUNK 32   // outputs per thread
#define TPB 256    // threads per block; one block per (n,c) row

// Native vector type for nontemporal stores (__builtin_nontemporal_store
// rejects HIP_vector_type; ext_vector_type is accepted and layout-identical).
typedef float vfloat4 __attribute__((ext_vector_type(4)));

__global__ __launch_bounds__(TPB) void causal_conv1d_kernel(
    const float* __restrict__ x,
    const float* __restrict__ w,
    const float* __restrict__ bias,
    float* __restrict__ out)
{
    const int row = blockIdx.x;            // row = n*DIMC + c
    const int c = row & (DIMC - 1);
    const float* __restrict__ xr = x + (size_t)row * LEN;
    float* __restrict__ outr = out + (size_t)row * LEN;

    const int t = threadIdx.x;
    const int base = t * CHUNK;            // first output index owned by this thread

    // ---- weights for this channel (block-uniform -> L1 broadcast) ----
    float wv[KW];
    {
        const float4* w4 = reinterpret_cast<const float4*>(w + (size_t)c * KW);
        #pragma unroll
        for (int i = 0; i < KW / 4; ++i) {
            float4 v = w4[i];
            wv[4*i+0] = v.x; wv[4*i+1] = v.y; wv[4*i+2] = v.z; wv[4*i+3] = v.w;
        }
    }
    const float bv = bias[c];

    // ---- load halo (previous 16 floats) + own 32 floats into registers ----
    // in[j] = x[base - 16 + j], j in [0, 48)
    float in[CHUNK + 16];
    if (t == 0) {
        #pragma unroll
        for (int i = 0; i < 16; ++i) in[i] = 0.0f;
    } else {
        const float4* p = reinterpret_cast<const float4*>(xr + base - 16);
        #pragma unroll
        for (int i = 0; i < 4; ++i) {
            float4 v = p[i];
            in[4*i+0] = v.x; in[4*i+1] = v.y; in[4*i+2] = v.z; in[4*i+3] = v.w;
        }
    }
    {
        const float4* p = reinterpret_cast<const float4*>(xr + base);
        #pragma unroll
        for (int i = 0; i < CHUNK / 4; ++i) {
            float4 v = p[i];
            in[16+4*i+0] = v.x; in[16+4*i+1] = v.y; in[16+4*i+2] = v.z; in[16+4*i+3] = v.w;
        }
    }

    // ---- sliding-window FMA, fully unrolled (static register indexing) ----
    // out[base+i] = sum_k x[base+i+k-15]*w[k] = sum_k in[i+k+1]*w[k]
    float acc[CHUNK];
    #pragma unroll
    for (int i = 0; i < CHUNK; ++i) {
        float a = bv;
        #pragma unroll
        for (int k = 0; k < KW; ++k) {
            a = fmaf(in[i + k + 1], wv[k], a);
        }
        acc[i] = a;
    }

    // ---- nontemporal vector stores (write-once output, don't thrash cache) ----
    vfloat4* o = reinterpret_cast<vfloat4*>(outr + base);
    #pragma unroll
    for (int i = 0; i < CHUNK / 4; ++i) {
        vfloat4 v;
        v.x = acc[4*i+0]; v.y = acc[4*i+1]; v.z = acc[4*i+2]; v.w = acc[4*i+3];
        __builtin_nontemporal_store(v, &o[i]);
    }
}

extern "C" void kernel_launch(void* const* d_in, const int* in_sizes, int n_in,
                              void* d_out, int out_size, void* d_ws, size_t ws_size,
                              hipStream_t stream) {
    const float* x    = (const float*)d_in[0];
    const float* w    = (const float*)d_in[1];
    const float* bias = (const float*)d_in[2];
    float* out = (float*)d_out;

    const int rows = 4 * DIMC;           // 8192 blocks, one per (n,c) row
    causal_conv1d_kernel<<<rows, TPB, 0, stream>>>(x, w, bias, out);
}

// Round 3
// 447.967 us; speedup vs baseline: 2.4931x; 2.4931x over previous
//
#include <hip/hip_runtime.h>

// Depthwise causal conv1d: x (4, 2048, 8192) f32, weight (2048,1,16) f32, bias (2048) f32.
// out[n,c,l] = sum_{k=0..15} x[n,c,l+k-15] * w[c,k] + bias[c]   (x index <0 -> 0)
// Memory-bound: ~512 MiB unique traffic -> ~85us floor @ 6.3 TB/s achievable.
//
// Round-2 lesson: big per-thread arrays (48+32 floats) went to SCRATCH
// (VGPR_Count=32, WRITE_SIZE 3x output). This version: one float4 output per
// thread, 20-float window (5x float4 loads), all instructions wave-coalesced
// (64 lanes x 16B = 1KB contiguous), tiny static arrays only.

#define DIMC 2048
#define LEN 8192
#define KW 16
#define TPB 256

typedef float vfloat4 __attribute__((ext_vector_type(4)));

__global__ __launch_bounds__(TPB) void causal_conv1d_kernel(
    const float* __restrict__ x,
    const float* __restrict__ w,
    const float* __restrict__ bias,
    float* __restrict__ out)
{
    // Flat float4 index over the whole (4*2048, 8192) tensor.
    const int gid = blockIdx.x * TPB + threadIdx.x;   // 0 .. 16777215
    const int l4  = gid & (LEN / 4 - 1);              // float4 index within row
    const int row = gid >> 11;                        // gid / (LEN/4)
    const int c   = row & (DIMC - 1);
    const float* __restrict__ xr = x + (size_t)row * LEN;
    const int l0 = l4 * 4;                            // first output element

    // ---- weights for this channel (uniform within block -> L1 broadcast) ----
    float wv[KW];
    {
        const vfloat4* w4 = reinterpret_cast<const vfloat4*>(w + (size_t)c * KW);
        #pragma unroll
        for (int i = 0; i < KW / 4; ++i) {
            vfloat4 v = w4[i];
            #pragma unroll
            for (int m = 0; m < 4; ++m) wv[4*i + m] = v[m];
        }
    }
    const float bv = bias[c];

    // ---- 20-float window: win[j] = x[row, l0 - 16 + j], zero-padded at row start ----
    // Clamped aligned loads + per-element select; uniform code, no divergent init.
    float win[20];
    #pragma unroll
    for (int j = 0; j < 5; ++j) {
        const int off  = l0 - 16 + 4 * j;             // multiple of 4 -> 16B aligned
        const int offc = off < 0 ? 0 : off;
        vfloat4 v = *reinterpret_cast<const vfloat4*>(xr + offc);
        #pragma unroll
        for (int m = 0; m < 4; ++m)
            win[4*j + m] = (off + m >= 0) ? v[m] : 0.0f;
    }

    // ---- 4 outputs: out[l0+i] = bias + sum_k win[i+k+1]*w[k] ----
    vfloat4 acc;
    #pragma unroll
    for (int i = 0; i < 4; ++i) {
        float a = bv;
        #pragma unroll
        for (int k = 0; k < KW; ++k)
            a = fmaf(win[i + k + 1], wv[k], a);
        acc[i] = a;
    }

    // ---- coalesced nontemporal store (full 64B lines per wave) ----
    __builtin_nontemporal_store(acc,
        reinterpret_cast<vfloat4*>(out + (size_t)row * LEN + l0));
}

extern "C" void kernel_launch(void* const* d_in, const int* in_sizes, int n_in,
                              void* d_out, int out_size, void* d_ws, size_t ws_size,
                              hipStream_t stream) {
    const float* x    = (const float*)d_in[0];
    const float* w    = (const float*)d_in[1];
    const float* bias = (const float*)d_in[2];
    float* out = (float*)d_out;

    // 4*2048*8192 floats / 4 per thread / 256 threads = 65536 blocks
    const int total_f4 = 4 * DIMC * LEN / 4;
    causal_conv1d_kernel<<<total_f4 / TPB, TPB, 0, stream>>>(x, w, bias, out);
}

// Round 4
// 415.930 us; speedup vs baseline: 2.6851x; 1.0770x over previous
//
#include <hip/hip_runtime.h>

// Depthwise causal conv1d: x (4, 2048, 8192) f32, weight (2048,1,16) f32, bias (2048) f32.
// out[n,c,l] = sum_{k=0..15} x[n,c,l+k-15] * w[c,k] + bias[c]   (x index <0 -> 0)
// Memory-bound: ~512 MiB unique traffic -> ~85us floor @ 6.3 TB/s achievable.
//
// R2 lesson: big per-thread arrays -> scratch spill (WRITE_SIZE 3x).
// R3 lesson: 1-float4/thread with 5x overlapping global loads + NT stores ~= 160us
//            (~2x off floor). Harness fills prove plain stores do 6.5 TB/s.
// R4: LDS-staged tile (1.0x coalesced global reads, window sharing via LDS,
//     conflict-free contiguous ds_read_b128), PLAIN coalesced float4 stores.

#define DIMC 2048
#define LEN 8192
#define KW 16
#define TPB 256
#define TILE 1024          // elements per block (256 threads x 1 float4)

typedef float vfloat4 __attribute__((ext_vector_type(4)));

__global__ __launch_bounds__(TPB) void causal_conv1d_kernel(
    const float* __restrict__ x,
    const float* __restrict__ w,
    const float* __restrict__ bias,
    float* __restrict__ out)
{
    // 8 tiles per row, 8192 rows -> 65536 blocks.
    const int bid  = blockIdx.x;
    const int row  = bid >> 3;                 // n*DIMC + c
    const int tile = (bid & 7) * TILE;         // start element within row
    const int c    = row & (DIMC - 1);
    const float* __restrict__ xr = x + (size_t)row * LEN;

    const int t = threadIdx.x;

    // lds[0..15] = halo x[tile-16 .. tile-1] (zeros for the row's first tile)
    // lds[16..16+TILE) = x[tile .. tile+TILE)
    __shared__ float lds[TILE + 16];

    // ---- stage main tile: coalesced, 1.0x traffic ----
    {
        vfloat4 mv = *reinterpret_cast<const vfloat4*>(xr + tile + t * 4);
        *reinterpret_cast<vfloat4*>(&lds[16 + t * 4]) = mv;
    }
    // ---- stage halo (4 threads) ----
    if (t < 4) {
        vfloat4 hv = {0.0f, 0.0f, 0.0f, 0.0f};
        if (tile != 0)
            hv = *reinterpret_cast<const vfloat4*>(xr + tile - 16 + t * 4);
        *reinterpret_cast<vfloat4*>(&lds[t * 4]) = hv;
    }

    // ---- weights + bias (uniform per block -> L1 broadcast) ----
    float wv[KW];
    {
        const vfloat4* w4 = reinterpret_cast<const vfloat4*>(w + (size_t)c * KW);
        #pragma unroll
        for (int i = 0; i < KW / 4; ++i) {
            vfloat4 v = w4[i];
            #pragma unroll
            for (int m = 0; m < 4; ++m) wv[4*i + m] = v[m];
        }
    }
    const float bv = bias[c];

    __syncthreads();

    // ---- window from LDS: win[u] = x[tile + t*4 - 16 + u] = lds[t*4 + u] ----
    // 5 x ds_read_b128, 16B-aligned, contiguous across lanes (conflict-free).
    float win[20];
    #pragma unroll
    for (int j = 0; j < 5; ++j) {
        vfloat4 v = *reinterpret_cast<const vfloat4*>(&lds[t * 4 + j * 4]);
        #pragma unroll
        for (int m = 0; m < 4; ++m) win[4*j + m] = v[m];
    }

    // ---- out[tile + t*4 + i] = bias + sum_k win[i+k+1]*w[k] ----
    vfloat4 acc;
    #pragma unroll
    for (int i = 0; i < 4; ++i) {
        float a = bv;
        #pragma unroll
        for (int k = 0; k < KW; ++k)
            a = fmaf(win[i + k + 1], wv[k], a);
        acc[i] = a;
    }

    // ---- plain coalesced store (fills prove this path does 6.5 TB/s) ----
    *reinterpret_cast<vfloat4*>(out + (size_t)row * LEN + tile + t * 4) = acc;
}

extern "C" void kernel_launch(void* const* d_in, const int* in_sizes, int n_in,
                              void* d_out, int out_size, void* d_ws, size_t ws_size,
                              hipStream_t stream) {
    const float* x    = (const float*)d_in[0];
    const float* w    = (const float*)d_in[1];
    const float* bias = (const float*)d_in[2];
    float* out = (float*)d_out;

    const int blocks = (4 * DIMC * LEN) / TILE;   // 65536
    causal_conv1d_kernel<<<blocks, TPB, 0, stream>>>(x, w, bias, out);
}